// Round 11
// baseline (149.523 us; speedup 1.0000x reference)
//
#include <hip/hip_runtime.h>
#include <hip/hip_bf16.h>

// Problem constants (from reference)
#define NB 4       // batch
#define CIN 32
#define TT 8       // time steps
#define NN 2000    // nodes
#define NE 16000   // edges
#define H1C 128
#define H2C 256
#define COUT 64
#define BT (NB*TT) // 32 graph replicas
#define CAP 40     // bucket capacity per dst node (max in-degree ~25 for Poisson(8))

// =============== kernel 1: bucket fill (blocks 0..62) + weight folding (63..70) ===============
__global__ __launch_bounds__(256) void k_fill(
    const int* __restrict__ src, const int* __restrict__ dst,
    const float* __restrict__ ew,
    const float* __restrict__ W1, const float* __restrict__ b1,
    const float* __restrict__ W2, const float* __restrict__ b2,
    const float* __restrict__ W3,
    int* __restrict__ cnt_g, int2* __restrict__ bucket,
    float* __restrict__ W123_g, float* __restrict__ d1_g, float* __restrict__ d2_g)
{
    const int tid = threadIdx.x;
    const int bx = blockIdx.x;

    if (bx < 63) {
        int e = bx * 256 + tid;
        if (e < NE) {
            int d = dst[e];
            int pos = atomicAdd(&cnt_g[d], 1);     // native global int atomic
            if (pos < CAP)
                bucket[d * CAP + pos] = make_int2(src[e], __float_as_int(ew[e]));
        }
        return;
    }

    // ---------- weight folding, 8-column slice ----------
    __shared__ float W3s[H2C][8];       // 8KB
    __shared__ float W23s[H1C + 1][8];  // rows 0..127 = W2@W3 slice, row 128 = b2@W3
    const int j0 = (bx - 63) * 8;

    for (int i = tid; i < H2C * 8; i += 256)
        W3s[i >> 3][i & 7] = W3[(size_t)(i >> 3) * COUT + j0 + (i & 7)];
    __syncthreads();

    for (int r = tid >> 3; r < H1C + 1; r += 32) {
        int j = tid & 7;
        const float* wrow = (r < H1C) ? (W2 + (size_t)r * H2C) : b2;
        float a0 = 0, a1 = 0, a2 = 0, a3 = 0;
        for (int k = 0; k < H2C; k += 4) {
            float4 wv = *(const float4*)(wrow + k);
            a0 += wv.x * W3s[k + 0][j];
            a1 += wv.y * W3s[k + 1][j];
            a2 += wv.z * W3s[k + 2][j];
            a3 += wv.w * W3s[k + 3][j];
        }
        W23s[r][j] = (a0 + a1) + (a2 + a3);
    }
    __syncthreads();

    for (int r = tid >> 3; r < CIN + 1; r += 32) {
        int j = tid & 7;
        const float* wrow = (r < CIN) ? (W1 + (size_t)r * H1C) : b1;
        float a0 = 0, a1 = 0, a2 = 0, a3 = 0;
        for (int k = 0; k < H1C; k += 4) {
            float4 wv = *(const float4*)(wrow + k);
            a0 += wv.x * W23s[k + 0][j];
            a1 += wv.y * W23s[k + 1][j];
            a2 += wv.z * W23s[k + 2][j];
            a3 += wv.w * W23s[k + 3][j];
        }
        float acc = (a0 + a1) + (a2 + a3);
        if (r < CIN) W123_g[(size_t)r * COUT + j0 + j] = acc;
        else         d1_g[j0 + j] = acc;
    }
    if (tid < 8) d2_g[j0 + tid] = W23s[H1C][tid];
}

// =============== kernel 2: S^3*X via in-place bucketed gather + r1/r2 block ===============
// grid (9, 32), 1024 threads:
//   x<8 : gather block (cg=x, bt=y): C3[bt][4cg..4cg+3][:] = S^3 x
//         S^3 = D^-1/2 (M D^-1)^3 D^1/2,  M = A_w + I.  Stored W_p = D^-1 V_p as
//         float4-per-node in LDS; pass = gather-to-regs -> barrier -> write-back.
//   x==8, y==0: r1 = S*1, r2 = S*r1.   x==8, y>0: exit.
__global__ __launch_bounds__(1024) void k_sss(
    const float* __restrict__ x,
    const int* __restrict__ cnt_g, const int2* __restrict__ bucket,
    float* __restrict__ r1f, float* __restrict__ r2f,
    float* __restrict__ C3)     // [bt][32][2000] channel-major
{
    __shared__ float Y[2048 * 4];   // 32KB: [node][4ch] float4 rows (gather) / dinv (r1r2)
    __shared__ float idg[2048];     // 8KB: 1/deg (gather) / u vector (r1r2)
    __shared__ int   cnts[2048];    // 8KB
    const int tid = threadIdx.x;
    const int bx = blockIdx.x, by = blockIdx.y;

    if (bx == 8) {
        if (by != 0) return;
        // ---------- r1/r2 ----------
        for (int n = tid; n < NN; n += 1024) {
            int c = cnt_g[n]; if (c > CAP) c = CAP;
            cnts[n] = c;
            const int2* row = bucket + n * CAP;
            float s = 1.0f;
            for (int k0 = 0; k0 < c; k0 += 8) {
                #pragma unroll
                for (int kk = 0; kk < 8; kk++)
                    if (k0 + kk < c) s += __int_as_float(row[k0 + kk].y);
            }
            Y[n] = 1.0f / sqrtf(s);        // dinv
        }
        __syncthreads();
        // r1[n] = dinv[n] * (dinv[n] + sum ew*dinv[col])
        for (int n = tid; n < NN; n += 1024) {
            const int2* row = bucket + n * CAP;
            int c = cnts[n];
            float a = Y[n];
            for (int k0 = 0; k0 < c; k0 += 8) {
                #pragma unroll
                for (int kk = 0; kk < 8; kk++)
                    if (k0 + kk < c) {
                        int2 e = row[k0 + kk];
                        a += __int_as_float(e.y) * Y[e.x];
                    }
            }
            float r = Y[n] * a;
            r1f[n] = r;
            idg[n] = Y[n] * r;             // u = dinv * r1
        }
        __syncthreads();
        // r2[n] = dinv[n] * (u[n] + sum ew*u[col])
        for (int n = tid; n < NN; n += 1024) {
            const int2* row = bucket + n * CAP;
            int c = cnts[n];
            float a = idg[n];
            for (int k0 = 0; k0 < c; k0 += 8) {
                #pragma unroll
                for (int kk = 0; kk < 8; kk++)
                    if (k0 + kk < c) {
                        int2 e = row[k0 + kk];
                        a += __int_as_float(e.y) * idg[e.x];
                    }
            }
            r2f[n] = Y[n] * a;
        }
        return;
    }

    // ---------- gather block ----------
    const int cg = bx, bt = by;
    const int b = bt >> 3, t = bt & 7;

    // deg -> idg, cache cnt
    for (int n = tid; n < NN; n += 1024) {
        int c = cnt_g[n]; if (c > CAP) c = CAP;
        cnts[n] = c;
        const int2* row = bucket + n * CAP;
        float s = 1.0f;
        for (int k0 = 0; k0 < c; k0 += 8) {
            #pragma unroll
            for (int kk = 0; kk < 8; kk++)
                if (k0 + kk < c) s += __int_as_float(row[k0 + kk].y);
        }
        idg[n] = 1.0f / s;
    }
    __syncthreads();

    // stage W0 = x * sqrt(idg)   (= D^-1 * D^{1/2} x)
    for (int n = tid; n < NN; n += 1024) {
        float sq = sqrtf(idg[n]);
        #pragma unroll
        for (int cc = 0; cc < 4; cc++)
            Y[(n << 2) + cc] =
                x[(((size_t)b * CIN + cg * 4 + cc) * TT + t) * NN + n] * sq;
    }
    __syncthreads();

    // three in-place passes: V[n] = W[n] + sum ew*W[col];  W <- V*idg
    const int n0 = tid, n1 = tid + 1024;
    for (int pass = 0; pass < 3; pass++) {
        float4 a0 = make_float4(0, 0, 0, 0), a1 = make_float4(0, 0, 0, 0);
        {   // node n0 (always < NN)
            float4 selfv = *(const float4*)&Y[n0 << 2];
            a0 = selfv;
            const int2* row = bucket + n0 * CAP;
            int c = cnts[n0];
            for (int k0 = 0; k0 < c; k0 += 8) {
                #pragma unroll
                for (int kk = 0; kk < 8; kk++)
                    if (k0 + kk < c) {
                        int2 e = row[k0 + kk];
                        float w = __int_as_float(e.y);
                        float4 yv = *(const float4*)&Y[e.x << 2];
                        a0.x += w * yv.x; a0.y += w * yv.y;
                        a0.z += w * yv.z; a0.w += w * yv.w;
                    }
            }
        }
        if (n1 < NN) {
            float4 selfv = *(const float4*)&Y[n1 << 2];
            a1 = selfv;
            const int2* row = bucket + n1 * CAP;
            int c = cnts[n1];
            for (int k0 = 0; k0 < c; k0 += 8) {
                #pragma unroll
                for (int kk = 0; kk < 8; kk++)
                    if (k0 + kk < c) {
                        int2 e = row[k0 + kk];
                        float w = __int_as_float(e.y);
                        float4 yv = *(const float4*)&Y[e.x << 2];
                        a1.x += w * yv.x; a1.y += w * yv.y;
                        a1.z += w * yv.z; a1.w += w * yv.w;
                    }
            }
        }
        if (pass < 2) {
            __syncthreads();   // all reads of Y done
            float g0 = idg[n0];
            *(float4*)&Y[n0 << 2] = make_float4(a0.x * g0, a0.y * g0, a0.z * g0, a0.w * g0);
            if (n1 < NN) {
                float g1 = idg[n1];
                *(float4*)&Y[n1 << 2] = make_float4(a1.x * g1, a1.y * g1, a1.z * g1, a1.w * g1);
            }
            __syncthreads();
        } else {
            // final: C3 = V3 * sqrt(idg), straight to global (coalesced per channel)
            float s0 = sqrtf(idg[n0]);
            float* base = C3 + ((size_t)bt * CIN + cg * 4) * NN;
            base[0 * NN + n0] = a0.x * s0;
            base[1 * NN + n0] = a0.y * s0;
            base[2 * NN + n0] = a0.z * s0;
            base[3 * NN + n0] = a0.w * s0;
            if (n1 < NN) {
                float s1 = sqrtf(idg[n1]);
                base[0 * NN + n1] = a1.x * s1;
                base[1 * NN + n1] = a1.y * s1;
                base[2 * NN + n1] = a1.z * s1;
                base[3 * NN + n1] = a1.w * s1;
            }
        }
    }
}

// =============== kernel 3: P = C3@W123 + r2*d1 + r1*d2 + b3; out = relu(P), transposed ===============
__global__ __launch_bounds__(256) void k_out(
    const float* __restrict__ C3,       // [bt][32][2000]
    const float* __restrict__ W123,     // 32x64
    const float* __restrict__ d1, const float* __restrict__ d2,
    const float* __restrict__ b3,
    const float* __restrict__ r1f, const float* __restrict__ r2f,
    float* __restrict__ out)            // [B][COUT][T][N]
{
    __shared__ float Cs[CIN][65];
    __shared__ float Ws[CIN][64];
    __shared__ float Os[64][65];
    __shared__ float d1s[64], d2s[64], b3s[64], r1s[64], r2s[64];
    const int tid = threadIdx.x;
    const int bt = blockIdx.y, b = bt >> 3, t = bt & 7;
    const int n0 = blockIdx.x * 64;

    for (int i = tid; i < CIN * 64; i += 256) {
        int ch = i >> 6, nn = i & 63;
        int n = n0 + nn;
        Cs[ch][nn] = (n < NN) ? C3[((size_t)bt * CIN + ch) * NN + n] : 0.f;
    }
    for (int i = tid; i < CIN * 64; i += 256)
        Ws[i >> 6][i & 63] = W123[i];
    if (tid < 64) {
        d1s[tid] = d1[tid];
        d2s[tid] = d2[tid];
        b3s[tid] = b3[tid];
        int n = n0 + tid;
        r1s[tid] = (n < NN) ? r1f[n] : 0.f;
        r2s[tid] = (n < NN) ? r2f[n] : 0.f;
    }
    __syncthreads();

    const int c = tid & 63, g = tid >> 6;
    for (int i = 0; i < 16; i++) {
        int nn = g * 16 + i;
        float acc = r2s[nn] * d1s[c] + r1s[nn] * d2s[c] + b3s[c];
        #pragma unroll
        for (int k = 0; k < CIN; k++) acc += Cs[k][nn] * Ws[k][c];
        Os[nn][c] = fmaxf(acc, 0.f);
    }
    __syncthreads();

    #pragma unroll
    for (int pass = 0; pass < 16; pass++) {
        int cc = g + pass * 4;
        int n = n0 + (tid & 63);
        if (n < NN)
            out[(((size_t)b * COUT + cc) * TT + t) * NN + n] = Os[tid & 63][cc];
    }
}

// ---------------- launch ----------------

extern "C" void kernel_launch(void* const* d_in, const int* in_sizes, int n_in,
                              void* d_out, int out_size, void* d_ws, size_t ws_size,
                              hipStream_t stream) {
    (void)in_sizes; (void)n_in; (void)out_size; (void)ws_size;

    const float* x  = (const float*)d_in[0];
    const int*   ei = (const int*)d_in[1];
    const float* ew = (const float*)d_in[2];
    const float* W1 = (const float*)d_in[3];
    const float* b1 = (const float*)d_in[4];
    const float* W2 = (const float*)d_in[5];
    const float* b2 = (const float*)d_in[6];
    const float* W3 = (const float*)d_in[7];
    const float* b3 = (const float*)d_in[8];
    float* out = (float*)d_out;

    const int* src = ei;
    const int* dst = ei + NE;

    // workspace layout (float units)
    float* wsf    = (float*)d_ws;
    int*   cnt_g  = (int*)wsf;                       // 2048 ints (re-zeroed each launch)
    int2*  bucket = (int2*)(wsf + 2048);             // 2000*CAP int2 = 160000 ints
    float* r1f    = wsf + 2048 + 2 * NN * CAP;       // 2048
    float* r2f    = r1f + 2048;                      // 2048
    float* W123   = r2f + 2048;                      // 2048
    float* d1     = W123 + 2048;                     // 64
    float* d2     = d1 + 64;                         // 64
    float* C3     = d2 + 64 + 64;                    // 32*32*2000 floats

    // zero bucket counters (graph-capturable)
    hipMemsetAsync(cnt_g, 0, 2048 * sizeof(int), stream);

    k_fill<<<dim3(71), dim3(256), 0, stream>>>(
        src, dst, ew, W1, b1, W2, b2, W3, cnt_g, bucket, W123, d1, d2);

    k_sss<<<dim3(9, BT), dim3(1024), 0, stream>>>(
        x, cnt_g, bucket, r1f, r2f, C3);

    k_out<<<dim3(32, BT), dim3(256), 0, stream>>>(
        C3, W123, d1, d2, b3, r1f, r2f, out);
}

// Round 13
// 100.729 us; speedup vs baseline: 1.4844x; 1.4844x over previous
//
#include <hip/hip_runtime.h>
#include <hip/hip_bf16.h>

// Problem constants (from reference)
#define NB 4       // batch
#define CIN 32
#define TT 8       // time steps
#define NN 2000    // nodes
#define NE 16000   // edges
#define H1C 128
#define H2C 256
#define COUT 64
#define BT (NB*TT) // 32 graph replicas
#define CAP 40     // bucket capacity per dst (max in-degree ~25 for Poisson(8))
#define BNN 2048   // bucket slot stride (nodes, padded)

// =============== kernel 1: bucket fill (blocks 0..62) + weight folding (63..70) ===============
// bucket is SLOT-MAJOR: bucket[k*BNN + d] = {src, ew} — coalesced reads in k_sss.
__global__ __launch_bounds__(256) void k_fill(
    const int* __restrict__ src, const int* __restrict__ dst,
    const float* __restrict__ ew,
    const float* __restrict__ W1, const float* __restrict__ b1,
    const float* __restrict__ W2, const float* __restrict__ b2,
    const float* __restrict__ W3,
    int* __restrict__ cnt_g, int2* __restrict__ bucket,
    float* __restrict__ W123_g, float* __restrict__ d1_g, float* __restrict__ d2_g)
{
    const int tid = threadIdx.x;
    const int bx = blockIdx.x;

    if (bx < 63) {
        int e = bx * 256 + tid;
        if (e < NE) {
            int d = dst[e];
            int pos = atomicAdd(&cnt_g[d], 1);     // native global int atomic
            if (pos < CAP)
                bucket[pos * BNN + d] = make_int2(src[e], __float_as_int(ew[e]));
        }
        return;
    }

    // ---------- weight folding, 8-column slice ----------
    __shared__ float W3s[H2C][8];       // 8KB
    __shared__ float W23s[H1C + 1][8];  // rows 0..127 = W2@W3 slice, row 128 = b2@W3
    const int j0 = (bx - 63) * 8;

    for (int i = tid; i < H2C * 8; i += 256)
        W3s[i >> 3][i & 7] = W3[(size_t)(i >> 3) * COUT + j0 + (i & 7)];
    __syncthreads();

    for (int r = tid >> 3; r < H1C + 1; r += 32) {
        int j = tid & 7;
        const float* wrow = (r < H1C) ? (W2 + (size_t)r * H2C) : b2;
        float a0 = 0, a1 = 0, a2 = 0, a3 = 0;
        for (int k = 0; k < H2C; k += 4) {
            float4 wv = *(const float4*)(wrow + k);
            a0 += wv.x * W3s[k + 0][j];
            a1 += wv.y * W3s[k + 1][j];
            a2 += wv.z * W3s[k + 2][j];
            a3 += wv.w * W3s[k + 3][j];
        }
        W23s[r][j] = (a0 + a1) + (a2 + a3);
    }
    __syncthreads();

    for (int r = tid >> 3; r < CIN + 1; r += 32) {
        int j = tid & 7;
        const float* wrow = (r < CIN) ? (W1 + (size_t)r * H1C) : b1;
        float a0 = 0, a1 = 0, a2 = 0, a3 = 0;
        for (int k = 0; k < H1C; k += 4) {
            float4 wv = *(const float4*)(wrow + k);
            a0 += wv.x * W23s[k + 0][j];
            a1 += wv.y * W23s[k + 1][j];
            a2 += wv.z * W23s[k + 2][j];
            a3 += wv.w * W23s[k + 3][j];
        }
        float acc = (a0 + a1) + (a2 + a3);
        if (r < CIN) W123_g[(size_t)r * COUT + j0 + j] = acc;
        else         d1_g[j0 + j] = acc;
    }
    if (tid < 8) d2_g[j0 + tid] = W23s[H1C][tid];
}

// =============== kernel 2: S^3*X via in-place coalesced-bucket gather + r1/r2 block ===============
// grid (9, 32), 1024 threads. Zero-padded slots (memset) -> no predication in inner loop.
__global__ __launch_bounds__(1024) void k_sss(
    const float* __restrict__ x,
    const int* __restrict__ cnt_g, const int2* __restrict__ bucket,
    float* __restrict__ r1f, float* __restrict__ r2f,
    float* __restrict__ C3)     // [bt][32][2000] channel-major
{
    __shared__ float4 Y[BNN];       // 32KB: [node] 4-channel vector (gather) / scalars (r1r2)
    __shared__ float  idg[BNN];     // 8KB
    __shared__ int    crs[BNN];     // 8KB: counts rounded up to 8
    const int tid = threadIdx.x;
    const int bx = blockIdx.x, by = blockIdx.y;

    if (bx == 8) {
        if (by != 0) return;
        // ---------- r1/r2 (scalar per node; Y.x = dinv, idg = u) ----------
        float* Ys = (float*)Y;
        for (int n = tid; n < NN; n += 1024) {
            int c = cnt_g[n]; if (c > CAP) c = CAP;
            int cr = (c + 7) & ~7;
            crs[n] = cr;
            float s = 1.0f;
            for (int k = 0; k < cr; k++)
                s += __int_as_float(bucket[k * BNN + n].y);   // zero-padded
            Ys[n] = 1.0f / sqrtf(s);
        }
        __syncthreads();
        for (int n = tid; n < NN; n += 1024) {
            int cr = crs[n];
            float a = Ys[n];
            for (int k = 0; k < cr; k++) {
                int2 e = bucket[k * BNN + n];
                a += __int_as_float(e.y) * Ys[e.x];
            }
            float r = Ys[n] * a;
            r1f[n] = r;
            idg[n] = Ys[n] * r;            // u = dinv * r1
        }
        __syncthreads();
        for (int n = tid; n < NN; n += 1024) {
            int cr = crs[n];
            float a = idg[n];
            for (int k = 0; k < cr; k++) {
                int2 e = bucket[k * BNN + n];
                a += __int_as_float(e.y) * idg[e.x];
            }
            r2f[n] = Ys[n] * a;
        }
        return;
    }

    // ---------- gather block ----------
    const int cg = bx, bt = by;
    const int b = bt >> 3, t = bt & 7;

    // deg -> idg (1/deg), rounded counts
    for (int n = tid; n < NN; n += 1024) {
        int c = cnt_g[n]; if (c > CAP) c = CAP;
        int cr = (c + 7) & ~7;
        crs[n] = cr;
        float s = 1.0f;
        for (int k = 0; k < cr; k++)
            s += __int_as_float(bucket[k * BNN + n].y);
        idg[n] = 1.0f / s;
    }
    __syncthreads();

    // stage W0 = x * sqrt(idg)   (= D^-1 * D^{1/2} x)
    for (int n = tid; n < NN; n += 1024) {
        float sq = sqrtf(idg[n]);
        float4 v;
        v.x = x[(((size_t)b * CIN + cg * 4 + 0) * TT + t) * NN + n] * sq;
        v.y = x[(((size_t)b * CIN + cg * 4 + 1) * TT + t) * NN + n] * sq;
        v.z = x[(((size_t)b * CIN + cg * 4 + 2) * TT + t) * NN + n] * sq;
        v.w = x[(((size_t)b * CIN + cg * 4 + 3) * TT + t) * NN + n] * sq;
        Y[n] = v;
    }
    __syncthreads();

    // three in-place passes: V[n] = W[n] + sum ew*W[col];  W <- V*idg
    const int n0 = tid, n1 = tid + 1024;
    for (int pass = 0; pass < 3; pass++) {
        float4 a0, a1;
        {   // node n0 (always < NN in padded range; crs[n>=NN]=0 via cnt_g=0)
            a0 = Y[n0];
            int cr = crs[n0];
            const int2* bp = bucket + n0;
            for (int k0 = 0; k0 < cr; k0 += 8) {
                int2 e0 = bp[(k0 + 0) * BNN];
                int2 e1 = bp[(k0 + 1) * BNN];
                int2 e2 = bp[(k0 + 2) * BNN];
                int2 e3 = bp[(k0 + 3) * BNN];
                int2 e4 = bp[(k0 + 4) * BNN];
                int2 e5 = bp[(k0 + 5) * BNN];
                int2 e6 = bp[(k0 + 6) * BNN];
                int2 e7 = bp[(k0 + 7) * BNN];
                float4 y0 = Y[e0.x], y1 = Y[e1.x], y2 = Y[e2.x], y3 = Y[e3.x];
                float4 y4 = Y[e4.x], y5 = Y[e5.x], y6 = Y[e6.x], y7 = Y[e7.x];
                float w0 = __int_as_float(e0.y), w1 = __int_as_float(e1.y);
                float w2 = __int_as_float(e2.y), w3 = __int_as_float(e3.y);
                float w4 = __int_as_float(e4.y), w5 = __int_as_float(e5.y);
                float w6 = __int_as_float(e6.y), w7 = __int_as_float(e7.y);
                a0.x += w0*y0.x + w1*y1.x + w2*y2.x + w3*y3.x + w4*y4.x + w5*y5.x + w6*y6.x + w7*y7.x;
                a0.y += w0*y0.y + w1*y1.y + w2*y2.y + w3*y3.y + w4*y4.y + w5*y5.y + w6*y6.y + w7*y7.y;
                a0.z += w0*y0.z + w1*y1.z + w2*y2.z + w3*y3.z + w4*y4.z + w5*y5.z + w6*y6.z + w7*y7.z;
                a0.w += w0*y0.w + w1*y1.w + w2*y2.w + w3*y3.w + w4*y4.w + w5*y5.w + w6*y6.w + w7*y7.w;
            }
        }
        if (n1 < NN) {
            a1 = Y[n1];
            int cr = crs[n1];
            const int2* bp = bucket + n1;
            for (int k0 = 0; k0 < cr; k0 += 8) {
                int2 e0 = bp[(k0 + 0) * BNN];
                int2 e1 = bp[(k0 + 1) * BNN];
                int2 e2 = bp[(k0 + 2) * BNN];
                int2 e3 = bp[(k0 + 3) * BNN];
                int2 e4 = bp[(k0 + 4) * BNN];
                int2 e5 = bp[(k0 + 5) * BNN];
                int2 e6 = bp[(k0 + 6) * BNN];
                int2 e7 = bp[(k0 + 7) * BNN];
                float4 y0 = Y[e0.x], y1 = Y[e1.x], y2 = Y[e2.x], y3 = Y[e3.x];
                float4 y4 = Y[e4.x], y5 = Y[e5.x], y6 = Y[e6.x], y7 = Y[e7.x];
                float w0 = __int_as_float(e0.y), w1 = __int_as_float(e1.y);
                float w2 = __int_as_float(e2.y), w3 = __int_as_float(e3.y);
                float w4 = __int_as_float(e4.y), w5 = __int_as_float(e5.y);
                float w6 = __int_as_float(e6.y), w7 = __int_as_float(e7.y);
                a1.x += w0*y0.x + w1*y1.x + w2*y2.x + w3*y3.x + w4*y4.x + w5*y5.x + w6*y6.x + w7*y7.x;
                a1.y += w0*y0.y + w1*y1.y + w2*y2.y + w3*y3.y + w4*y4.y + w5*y5.y + w6*y6.y + w7*y7.y;
                a1.z += w0*y0.z + w1*y1.z + w2*y2.z + w3*y3.z + w4*y4.z + w5*y5.z + w6*y6.z + w7*y7.z;
                a1.w += w0*y0.w + w1*y1.w + w2*y2.w + w3*y3.w + w4*y4.w + w5*y5.w + w6*y6.w + w7*y7.w;
            }
        }
        if (pass < 2) {
            __syncthreads();   // all reads of Y done
            float g0 = idg[n0];
            Y[n0] = make_float4(a0.x * g0, a0.y * g0, a0.z * g0, a0.w * g0);
            if (n1 < NN) {
                float g1 = idg[n1];
                Y[n1] = make_float4(a1.x * g1, a1.y * g1, a1.z * g1, a1.w * g1);
            }
            __syncthreads();
        } else {
            // final: C3 = V3 * sqrt(idg), straight to global (coalesced per channel)
            float s0 = sqrtf(idg[n0]);
            float* base = C3 + ((size_t)bt * CIN + cg * 4) * NN;
            base[0 * NN + n0] = a0.x * s0;
            base[1 * NN + n0] = a0.y * s0;
            base[2 * NN + n0] = a0.z * s0;
            base[3 * NN + n0] = a0.w * s0;
            if (n1 < NN) {
                float s1 = sqrtf(idg[n1]);
                base[0 * NN + n1] = a1.x * s1;
                base[1 * NN + n1] = a1.y * s1;
                base[2 * NN + n1] = a1.z * s1;
                base[3 * NN + n1] = a1.w * s1;
            }
        }
    }
}

// =============== kernel 3: P = C3@W123 + r2*d1 + r1*d2 + b3; out = relu(P), transposed ===============
__global__ __launch_bounds__(256) void k_out(
    const float* __restrict__ C3,       // [bt][32][2000]
    const float* __restrict__ W123,     // 32x64
    const float* __restrict__ d1, const float* __restrict__ d2,
    const float* __restrict__ b3,
    const float* __restrict__ r1f, const float* __restrict__ r2f,
    float* __restrict__ out)            // [B][COUT][T][N]
{
    __shared__ float Cs[CIN][65];
    __shared__ float Ws[CIN][64];
    __shared__ float Os[64][65];
    __shared__ float d1s[64], d2s[64], b3s[64], r1s[64], r2s[64];
    const int tid = threadIdx.x;
    const int bt = blockIdx.y, b = bt >> 3, t = bt & 7;
    const int n0 = blockIdx.x * 64;

    for (int i = tid; i < CIN * 64; i += 256) {
        int ch = i >> 6, nn = i & 63;
        int n = n0 + nn;
        Cs[ch][nn] = (n < NN) ? C3[((size_t)bt * CIN + ch) * NN + n] : 0.f;
    }
    for (int i = tid; i < CIN * 64; i += 256)
        Ws[i >> 6][i & 63] = W123[i];
    if (tid < 64) {
        d1s[tid] = d1[tid];
        d2s[tid] = d2[tid];
        b3s[tid] = b3[tid];
        int n = n0 + tid;
        r1s[tid] = (n < NN) ? r1f[n] : 0.f;
        r2s[tid] = (n < NN) ? r2f[n] : 0.f;
    }
    __syncthreads();

    const int c = tid & 63, g = tid >> 6;
    for (int i = 0; i < 16; i++) {
        int nn = g * 16 + i;
        float acc = r2s[nn] * d1s[c] + r1s[nn] * d2s[c] + b3s[c];
        #pragma unroll
        for (int k = 0; k < CIN; k++) acc += Cs[k][nn] * Ws[k][c];
        Os[nn][c] = fmaxf(acc, 0.f);
    }
    __syncthreads();

    #pragma unroll
    for (int pass = 0; pass < 16; pass++) {
        int cc = g + pass * 4;
        int n = n0 + (tid & 63);
        if (n < NN)
            out[(((size_t)b * COUT + cc) * TT + t) * NN + n] = Os[tid & 63][cc];
    }
}

// ---------------- launch ----------------

extern "C" void kernel_launch(void* const* d_in, const int* in_sizes, int n_in,
                              void* d_out, int out_size, void* d_ws, size_t ws_size,
                              hipStream_t stream) {
    (void)in_sizes; (void)n_in; (void)out_size; (void)ws_size;

    const float* x  = (const float*)d_in[0];
    const int*   ei = (const int*)d_in[1];
    const float* ew = (const float*)d_in[2];
    const float* W1 = (const float*)d_in[3];
    const float* b1 = (const float*)d_in[4];
    const float* W2 = (const float*)d_in[5];
    const float* b2 = (const float*)d_in[6];
    const float* W3 = (const float*)d_in[7];
    const float* b3 = (const float*)d_in[8];
    float* out = (float*)d_out;

    const int* src = ei;
    const int* dst = ei + NE;

    // workspace layout (float units). cnt_g + bucket contiguous -> one memset.
    float* wsf    = (float*)d_ws;
    int*   cnt_g  = (int*)wsf;                       // 2048 ints
    int2*  bucket = (int2*)(wsf + 2048);             // CAP*BNN int2 (slot-major)
    float* r1f    = wsf + 2048 + 2 * CAP * BNN;      // 2048
    float* r2f    = r1f + 2048;                      // 2048
    float* W123   = r2f + 2048;                      // 2048
    float* d1     = W123 + 2048;                     // 64
    float* d2     = d1 + 64;                         // 64
    float* C3     = d2 + 64 + 64;                    // 32*32*2000 floats

    // zero counters + bucket (zero-padded slots; graph-capturable)
    hipMemsetAsync(cnt_g, 0, (2048 + 2 * CAP * BNN) * sizeof(int), stream);

    k_fill<<<dim3(71), dim3(256), 0, stream>>>(
        src, dst, ew, W1, b1, W2, b2, W3, cnt_g, bucket, W123, d1, d2);

    k_sss<<<dim3(9, BT), dim3(1024), 0, stream>>>(
        x, cnt_g, bucket, r1f, r2f, C3);

    k_out<<<dim3(32, BT), dim3(256), 0, stream>>>(
        C3, W123, d1, d2, b3, r1f, r2f, out);
}

// Round 15
// 87.421 us; speedup vs baseline: 1.7104x; 1.1522x over previous
//
#include <hip/hip_runtime.h>
#include <hip/hip_bf16.h>

// Problem constants (from reference)
#define NB 4       // batch
#define CIN 32
#define TT 8       // time steps
#define NN 2000    // nodes
#define NE 16000   // edges
#define H1C 128
#define H2C 256
#define COUT 64
#define BT (NB*TT) // 32 graph replicas
#define CAP 40     // bucket capacity per dst (max in-degree ~25 for Poisson(8))
#define BNN 2048   // bucket slot stride (nodes, padded)
#define WINV (1.0f/65535.0f)

// =============== kernel 1: bucket fill (blocks 0..62) + weight folding (63..70) ===============
// bucket is SLOT-MAJOR packed u32: bucket[k*BNN + d] = (src<<16) | u16(ew*65535).
__global__ __launch_bounds__(256) void k_fill(
    const int* __restrict__ src, const int* __restrict__ dst,
    const float* __restrict__ ew,
    const float* __restrict__ W1, const float* __restrict__ b1,
    const float* __restrict__ W2, const float* __restrict__ b2,
    const float* __restrict__ W3,
    int* __restrict__ cnt_g, unsigned int* __restrict__ bucket,
    float* __restrict__ W123_g, float* __restrict__ d1_g, float* __restrict__ d2_g)
{
    const int tid = threadIdx.x;
    const int bx = blockIdx.x;

    if (bx < 63) {
        int e = bx * 256 + tid;
        if (e < NE) {
            int d = dst[e];
            unsigned int w16 = __float2uint_rn(ew[e] * 65535.0f);
            if (w16 > 65535u) w16 = 65535u;
            int pos = atomicAdd(&cnt_g[d], 1);     // native global int atomic
            if (pos < CAP)
                bucket[pos * BNN + d] = ((unsigned int)src[e] << 16) | w16;
        }
        return;
    }

    // ---------- weight folding, 8-column slice ----------
    __shared__ float W3s[H2C][8];       // 8KB
    __shared__ float W23s[H1C + 1][8];  // rows 0..127 = W2@W3 slice, row 128 = b2@W3
    const int j0 = (bx - 63) * 8;

    for (int i = tid; i < H2C * 8; i += 256)
        W3s[i >> 3][i & 7] = W3[(size_t)(i >> 3) * COUT + j0 + (i & 7)];
    __syncthreads();

    for (int r = tid >> 3; r < H1C + 1; r += 32) {
        int j = tid & 7;
        const float* wrow = (r < H1C) ? (W2 + (size_t)r * H2C) : b2;
        float a0 = 0, a1 = 0, a2 = 0, a3 = 0;
        for (int k = 0; k < H2C; k += 4) {
            float4 wv = *(const float4*)(wrow + k);
            a0 += wv.x * W3s[k + 0][j];
            a1 += wv.y * W3s[k + 1][j];
            a2 += wv.z * W3s[k + 2][j];
            a3 += wv.w * W3s[k + 3][j];
        }
        W23s[r][j] = (a0 + a1) + (a2 + a3);
    }
    __syncthreads();

    for (int r = tid >> 3; r < CIN + 1; r += 32) {
        int j = tid & 7;
        const float* wrow = (r < CIN) ? (W1 + (size_t)r * H1C) : b1;
        float a0 = 0, a1 = 0, a2 = 0, a3 = 0;
        for (int k = 0; k < H1C; k += 4) {
            float4 wv = *(const float4*)(wrow + k);
            a0 += wv.x * W23s[k + 0][j];
            a1 += wv.y * W23s[k + 1][j];
            a2 += wv.z * W23s[k + 2][j];
            a3 += wv.w * W23s[k + 3][j];
        }
        float acc = (a0 + a1) + (a2 + a3);
        if (r < CIN) W123_g[(size_t)r * COUT + j0 + j] = acc;
        else         d1_g[j0 + j] = acc;
    }
    if (tid < 8) d2_g[j0 + tid] = W23s[H1C][tid];
}

// =============== kernel 2: S^3*X with the graph COMPACTED INTO LDS ===============
// grid (8, 32), 1024 threads: cg=blockIdx.x (4 channels), bt=blockIdx.y.
// Per block: scan cnt -> CSR rowptr in LDS; compact bucket -> 64KB LDS edge array
// (+deg on the fly); 3 propagation passes run entirely from LDS.
// Block (0,0) additionally computes r1 = S*1, r2 = S*r1 before staging.
__global__ __launch_bounds__(1024) void k_sss(
    const float* __restrict__ x,
    const int* __restrict__ cnt_g, const unsigned int* __restrict__ bucket,
    float* __restrict__ r1f, float* __restrict__ r2f,
    float* __restrict__ C3)     // [bt][32][2000] channel-major
{
    __shared__ unsigned int cmp[NE];   // 64000 B compacted edges (CSR order)
    __shared__ float4 Y[BNN];          // 32768 B: [node] 4-channel vector
    __shared__ float  idg[BNN];        // 8192 B: 1/deg
    __shared__ unsigned int rp[BNN + 1]; // 8196 B rowptr
    __shared__ int ssc[256];           // scan temp / maxc

    const int tid = threadIdx.x;
    const int cg = blockIdx.x, bt = blockIdx.y;
    const int b = bt >> 3, t = bt & 7;

    // ---- scan of clamped counts -> rp (threads 0..255, 8 elems each) ----
    int local[8];
    if (tid < 256) {
        int base = tid * 8, sum = 0;
        #pragma unroll
        for (int i = 0; i < 8; i++) {
            int c = cnt_g[base + i];
            if (c > CAP) c = CAP;
            local[i] = sum;
            sum += c;
        }
        ssc[tid] = sum;
    }
    __syncthreads();
    for (int off = 1; off < 256; off <<= 1) {
        int v = 0;
        if (tid < 256 && tid >= off) v = ssc[tid - off];
        __syncthreads();
        if (tid < 256 && tid >= off) ssc[tid] += v;
        __syncthreads();
    }
    if (tid < 256) {
        int ce = (tid > 0) ? ssc[tid - 1] : 0;
        int base = tid * 8;
        #pragma unroll
        for (int i = 0; i < 8; i++) rp[base + i] = ce + local[i];
        if (tid == 255) rp[BNN] = ssc[255];
    }
    __syncthreads();

    // ---- block max degree ----
    const int n0 = tid, n1 = tid + 1024;
    const unsigned int rp0 = rp[n0], re0 = rp[n0 + 1];
    const unsigned int rp1 = rp[n1], re1 = rp[n1 + 1];
    const int cn0 = (int)(re0 - rp0), cn1 = (int)(re1 - rp1);
    if (tid == 0) ssc[0] = 0;
    __syncthreads();
    atomicMax(&ssc[0], max(cn0, cn1));
    __syncthreads();
    const int maxc = ssc[0];

    // ---- compact bucket -> LDS CSR, accumulate deg (no atomics) ----
    float dg0 = 0.f, dg1 = 0.f;
    for (int k = 0; k < maxc; k++) {
        if (k < cn0) {
            unsigned int g = bucket[k * BNN + n0];
            cmp[rp0 + k] = g;
            dg0 += (float)(g & 0xffffu);
        }
        if (k < cn1) {
            unsigned int g = bucket[k * BNN + n1];
            cmp[rp1 + k] = g;
            dg1 += (float)(g & 0xffffu);
        }
    }
    idg[n0] = 1.0f / (1.0f + dg0 * WINV);
    idg[n1] = 1.0f / (1.0f + dg1 * WINV);
    __syncthreads();

    // ---- block (0,0): r1 = S*1, r2 = S*r1 from the LDS CSR (Y as scratch) ----
    if (cg == 0 && bt == 0) {
        float* Ys = (float*)Y;   // 8192 floats: [0..2047]=dinv, [2048..4095]=v
        for (int n = tid; n < BNN; n += 1024) Ys[n] = sqrtf(idg[n]);
        __syncthreads();
        for (int n = tid; n < NN; n += 1024) {
            float s = 0.f;
            for (unsigned int p = rp[n]; p < rp[n + 1]; p++) {
                unsigned int g = cmp[p];
                s += (float)(g & 0xffffu) * Ys[g >> 16];
            }
            float r = Ys[n] * (Ys[n] + s * WINV);
            r1f[n] = r;
            Ys[BNN + n] = Ys[n] * r;
        }
        __syncthreads();
        for (int n = tid; n < NN; n += 1024) {
            float s = 0.f;
            for (unsigned int p = rp[n]; p < rp[n + 1]; p++) {
                unsigned int g = cmp[p];
                s += (float)(g & 0xffffu) * Ys[BNN + (g >> 16)];
            }
            r2f[n] = Ys[n] * (Ys[BNN + n] + s * WINV);
        }
        __syncthreads();
    }

    // ---- stage W0 = x * sqrt(idg)  (= D^-1 D^{1/2} x) ----
    for (int n = tid; n < NN; n += 1024) {
        float sq = sqrtf(idg[n]);
        float4 v;
        v.x = x[(((size_t)b * CIN + cg * 4 + 0) * TT + t) * NN + n] * sq;
        v.y = x[(((size_t)b * CIN + cg * 4 + 1) * TT + t) * NN + n] * sq;
        v.z = x[(((size_t)b * CIN + cg * 4 + 2) * TT + t) * NN + n] * sq;
        v.w = x[(((size_t)b * CIN + cg * 4 + 3) * TT + t) * NN + n] * sq;
        Y[n] = v;
    }
    __syncthreads();

    // ---- three passes, all LDS: a = Y[n] + (1/65535)*sum w16*Y[src] ----
    for (int pass = 0; pass < 3; pass++) {
        float4 a0 = Y[n0];
        {
            float sx = 0, sy = 0, sz = 0, sw = 0;
            for (unsigned int p = rp0; p < re0; p++) {
                unsigned int g = cmp[p];
                float w = (float)(g & 0xffffu);
                float4 y = Y[g >> 16];
                sx += w * y.x; sy += w * y.y; sz += w * y.z; sw += w * y.w;
            }
            a0.x += sx * WINV; a0.y += sy * WINV;
            a0.z += sz * WINV; a0.w += sw * WINV;
        }
        float4 a1 = Y[n1];
        {
            float sx = 0, sy = 0, sz = 0, sw = 0;
            for (unsigned int p = rp1; p < re1; p++) {
                unsigned int g = cmp[p];
                float w = (float)(g & 0xffffu);
                float4 y = Y[g >> 16];
                sx += w * y.x; sy += w * y.y; sz += w * y.z; sw += w * y.w;
            }
            a1.x += sx * WINV; a1.y += sy * WINV;
            a1.z += sz * WINV; a1.w += sw * WINV;
        }
        if (pass < 2) {
            __syncthreads();   // all reads of Y done
            float g0 = idg[n0];
            Y[n0] = make_float4(a0.x * g0, a0.y * g0, a0.z * g0, a0.w * g0);
            float g1 = idg[n1];
            Y[n1] = make_float4(a1.x * g1, a1.y * g1, a1.z * g1, a1.w * g1);
            __syncthreads();
        } else {
            // final: C3 = a * sqrt(idg), straight to global (coalesced per channel)
            float s0 = sqrtf(idg[n0]);
            float* base = C3 + ((size_t)bt * CIN + cg * 4) * NN;
            base[0 * NN + n0] = a0.x * s0;
            base[1 * NN + n0] = a0.y * s0;
            base[2 * NN + n0] = a0.z * s0;
            base[3 * NN + n0] = a0.w * s0;
            if (n1 < NN) {
                float s1 = sqrtf(idg[n1]);
                base[0 * NN + n1] = a1.x * s1;
                base[1 * NN + n1] = a1.y * s1;
                base[2 * NN + n1] = a1.z * s1;
                base[3 * NN + n1] = a1.w * s1;
            }
        }
    }
}

// =============== kernel 3: P = C3@W123 + r2*d1 + r1*d2 + b3; out = relu(P), transposed ===============
__global__ __launch_bounds__(256) void k_out(
    const float* __restrict__ C3,       // [bt][32][2000]
    const float* __restrict__ W123,     // 32x64
    const float* __restrict__ d1, const float* __restrict__ d2,
    const float* __restrict__ b3,
    const float* __restrict__ r1f, const float* __restrict__ r2f,
    float* __restrict__ out)            // [B][COUT][T][N]
{
    __shared__ float Cs[CIN][65];
    __shared__ float Ws[CIN][64];
    __shared__ float Os[64][65];
    __shared__ float d1s[64], d2s[64], b3s[64], r1s[64], r2s[64];
    const int tid = threadIdx.x;
    const int bt = blockIdx.y, b = bt >> 3, t = bt & 7;
    const int n0 = blockIdx.x * 64;

    for (int i = tid; i < CIN * 64; i += 256) {
        int ch = i >> 6, nn = i & 63;
        int n = n0 + nn;
        Cs[ch][nn] = (n < NN) ? C3[((size_t)bt * CIN + ch) * NN + n] : 0.f;
    }
    for (int i = tid; i < CIN * 64; i += 256)
        Ws[i >> 6][i & 63] = W123[i];
    if (tid < 64) {
        d1s[tid] = d1[tid];
        d2s[tid] = d2[tid];
        b3s[tid] = b3[tid];
        int n = n0 + tid;
        r1s[tid] = (n < NN) ? r1f[n] : 0.f;
        r2s[tid] = (n < NN) ? r2f[n] : 0.f;
    }
    __syncthreads();

    const int c = tid & 63, g = tid >> 6;
    for (int i = 0; i < 16; i++) {
        int nn = g * 16 + i;
        float acc = r2s[nn] * d1s[c] + r1s[nn] * d2s[c] + b3s[c];
        #pragma unroll
        for (int k = 0; k < CIN; k++) acc += Cs[k][nn] * Ws[k][c];
        Os[nn][c] = fmaxf(acc, 0.f);
    }
    __syncthreads();

    #pragma unroll
    for (int pass = 0; pass < 16; pass++) {
        int cc = g + pass * 4;
        int n = n0 + (tid & 63);
        if (n < NN)
            out[(((size_t)b * COUT + cc) * TT + t) * NN + n] = Os[tid & 63][cc];
    }
}

// ---------------- launch ----------------

extern "C" void kernel_launch(void* const* d_in, const int* in_sizes, int n_in,
                              void* d_out, int out_size, void* d_ws, size_t ws_size,
                              hipStream_t stream) {
    (void)in_sizes; (void)n_in; (void)out_size; (void)ws_size;

    const float* x  = (const float*)d_in[0];
    const int*   ei = (const int*)d_in[1];
    const float* ew = (const float*)d_in[2];
    const float* W1 = (const float*)d_in[3];
    const float* b1 = (const float*)d_in[4];
    const float* W2 = (const float*)d_in[5];
    const float* b2 = (const float*)d_in[6];
    const float* W3 = (const float*)d_in[7];
    const float* b3 = (const float*)d_in[8];
    float* out = (float*)d_out;

    const int* src = ei;
    const int* dst = ei + NE;

    // workspace layout (float units)
    float* wsf    = (float*)d_ws;
    int*   cnt_g  = (int*)wsf;                        // 2048 ints (re-zeroed)
    unsigned int* bucket = (unsigned int*)(wsf + 2048); // CAP*BNN u32 (slot-major, garbage-tolerant)
    float* r1f    = wsf + 2048 + CAP * BNN;           // 2048
    float* r2f    = r1f + 2048;                       // 2048
    float* W123   = r2f + 2048;                       // 2048
    float* d1     = W123 + 2048;                      // 64
    float* d2     = d1 + 64;                          // 64
    float* C3     = d2 + 64 + 64;                     // 32*32*2000 floats

    // zero only the counters (bucket garbage is never read: predicated compaction)
    hipMemsetAsync(cnt_g, 0, 2048 * sizeof(int), stream);

    k_fill<<<dim3(71), dim3(256), 0, stream>>>(
        src, dst, ew, W1, b1, W2, b2, W3, cnt_g, bucket, W123, d1, d2);

    k_sss<<<dim3(8, BT), dim3(1024), 0, stream>>>(
        x, cnt_g, bucket, r1f, r2f, C3);

    k_out<<<dim3(32, BT), dim3(256), 0, stream>>>(
        C3, W123, d1, d2, b3, r1f, r2f, out);
}

// Round 18
// 59.471 us; speedup vs baseline: 2.5142x; 1.4700x over previous
//
#include <hip/hip_runtime.h>
#include <hip/hip_bf16.h>

// Problem constants (from reference)
#define NB 4       // batch
#define CIN 32
#define TT 8       // time steps
#define NN 2000    // nodes
#define NE 16000   // edges
#define H1C 128
#define H2C 256
#define COUT 64
#define BT (NB*TT) // 32 graph replicas
#define BNN 2048   // padded node count
#define WINV (1.0f/65535.0f)

// =============== kernel 1: fully self-contained S^3*X ===============
// grid (8, 32) = 256 blocks (1 per CU), 1024 threads.
// Every block: builds the EXACT CSR from raw src/dst/ew in LDS (count -> scan ->
// fill, native int LDS atomics), computes deg, stages x, runs 3 LDS propagation
// passes, stores C3[bt][4cg..4cg+3][:].
// Blocks with bt==1 additionally fold weights (8-col slice each) first.
// Block (0,0) additionally computes r1 = S*1, r2 = S*r1.
__global__ __launch_bounds__(1024) void k_sss(
    const float* __restrict__ x,
    const int* __restrict__ src, const int* __restrict__ dst,
    const float* __restrict__ ew,
    const float* __restrict__ W1, const float* __restrict__ b1,
    const float* __restrict__ W2, const float* __restrict__ b2,
    const float* __restrict__ W3,
    float* __restrict__ r1f, float* __restrict__ r2f,
    float* __restrict__ W123_g, float* __restrict__ d1_g, float* __restrict__ d2_g,
    float* __restrict__ C3)     // [bt][32][2000] channel-major
{
    __shared__ unsigned int cmp[NE];     // 64000 B packed edges (src<<16 | w16), CSR order
    __shared__ float4 Y[BNN];            // 32768 B node feature vectors (4 ch)
    __shared__ float  idg[BNN];          // 8192 B 1/deg
    __shared__ unsigned int rp[BNN + 1]; // 8196 B rowptr
    __shared__ int cc_[BNN];             // 8192 B count, then cur
    __shared__ int ssc[256];             // 1024 B scan temp

    const int tid = threadIdx.x;
    const int cg = blockIdx.x, bt = blockIdx.y;
    const int b = bt >> 3, t = bt & 7;

    // ---- weight folding (blocks bt==1 only), cmp region as scratch ----
    if (bt == 1) {
        float* W3s  = (float*)cmp;            // 2048 floats
        float* W23s = (float*)cmp + H2C * 8;  // 1032 floats (rows 0..127 = W2@W3, 128 = b2@W3)
        const int j0 = cg * 8;

        for (int i = tid; i < H2C * 8; i += 1024)
            W3s[i] = W3[(size_t)(i >> 3) * COUT + j0 + (i & 7)];
        __syncthreads();

        for (int r = tid >> 3; r < H1C + 1; r += 128) {
            int j = tid & 7;
            const float* wrow = (r < H1C) ? (W2 + (size_t)r * H2C) : b2;
            float a0 = 0, a1 = 0, a2 = 0, a3 = 0;
            for (int k = 0; k < H2C; k += 4) {
                float4 wv = *(const float4*)(wrow + k);
                a0 += wv.x * W3s[(k + 0) * 8 + j];
                a1 += wv.y * W3s[(k + 1) * 8 + j];
                a2 += wv.z * W3s[(k + 2) * 8 + j];
                a3 += wv.w * W3s[(k + 3) * 8 + j];
            }
            W23s[r * 8 + j] = (a0 + a1) + (a2 + a3);
        }
        __syncthreads();

        for (int r = tid >> 3; r < CIN + 1; r += 128) {
            int j = tid & 7;
            const float* wrow = (r < CIN) ? (W1 + (size_t)r * H1C) : b1;
            float a0 = 0, a1 = 0, a2 = 0, a3 = 0;
            for (int k = 0; k < H1C; k += 4) {
                float4 wv = *(const float4*)(wrow + k);
                a0 += wv.x * W23s[(k + 0) * 8 + j];
                a1 += wv.y * W23s[(k + 1) * 8 + j];
                a2 += wv.z * W23s[(k + 2) * 8 + j];
                a3 += wv.w * W23s[(k + 3) * 8 + j];
            }
            float acc = (a0 + a1) + (a2 + a3);
            if (r < CIN) W123_g[(size_t)r * COUT + j0 + j] = acc;
            else         d1_g[j0 + j] = acc;
        }
        if (tid < 8) d2_g[j0 + tid] = W23s[H1C * 8 + tid];
        __syncthreads();   // cmp scratch free again
    }

    // ---- build exact CSR in LDS: count -> scan -> fill ----
    for (int i = tid; i < BNN; i += 1024) cc_[i] = 0;
    __syncthreads();
    #pragma unroll
    for (int i = 0; i < 16; i++) {
        int e = tid + i * 1024;
        if (e < NE) atomicAdd(&cc_[dst[e]], 1);    // native ds_add
    }
    __syncthreads();

    int local[8];
    if (tid < 256) {
        int base = tid * 8, sum = 0;
        #pragma unroll
        for (int i = 0; i < 8; i++) {
            int v = cc_[base + i];
            local[i] = sum;
            sum += v;
        }
        ssc[tid] = sum;
    }
    __syncthreads();
    for (int off = 1; off < 256; off <<= 1) {
        int v = 0;
        if (tid < 256 && tid >= off) v = ssc[tid - off];
        __syncthreads();
        if (tid < 256 && tid >= off) ssc[tid] += v;
        __syncthreads();
    }
    if (tid < 256) {
        int ce = (tid > 0) ? ssc[tid - 1] : 0;
        int base = tid * 8;
        #pragma unroll
        for (int i = 0; i < 8; i++) {
            int v = ce + local[i];
            rp[base + i] = v;
            cc_[base + i] = v;      // cur
        }
        if (tid == 255) rp[BNN] = ssc[255];
    }
    __syncthreads();

    #pragma unroll
    for (int i = 0; i < 16; i++) {
        int e = tid + i * 1024;
        if (e < NE) {
            int d = dst[e];
            unsigned int w16 = __float2uint_rn(ew[e] * 65535.0f);
            if (w16 > 65535u) w16 = 65535u;
            int pos = atomicAdd(&cc_[d], 1);       // native ds_add_rtn
            cmp[pos] = ((unsigned int)src[e] << 16) | w16;
        }
    }
    __syncthreads();

    // ---- deg -> idg ----
    for (int n = tid; n < BNN; n += 1024) {
        float s = 0.f;
        for (unsigned int p = rp[n]; p < rp[n + 1]; p++)
            s += (float)(cmp[p] & 0xffffu);
        idg[n] = 1.0f / (1.0f + s * WINV);
    }
    __syncthreads();

    // ---- block (0,0): r1 = S*1, r2 = S*r1 (Y as scalar scratch) ----
    if (cg == 0 && bt == 0) {
        float* Ys = (float*)Y;   // [0..2047]=dinv, [2048..4095]=u
        for (int n = tid; n < BNN; n += 1024) Ys[n] = sqrtf(idg[n]);
        __syncthreads();
        for (int n = tid; n < NN; n += 1024) {
            float s = 0.f;
            for (unsigned int p = rp[n]; p < rp[n + 1]; p++) {
                unsigned int g = cmp[p];
                s += (float)(g & 0xffffu) * Ys[g >> 16];
            }
            float r = Ys[n] * (Ys[n] + s * WINV);
            r1f[n] = r;
            Ys[BNN + n] = Ys[n] * r;
        }
        __syncthreads();
        for (int n = tid; n < NN; n += 1024) {
            float s = 0.f;
            for (unsigned int p = rp[n]; p < rp[n + 1]; p++) {
                unsigned int g = cmp[p];
                s += (float)(g & 0xffffu) * Ys[BNN + (g >> 16)];
            }
            r2f[n] = Ys[n] * (Ys[BNN + n] + s * WINV);
        }
        __syncthreads();
    }

    // ---- stage W0 = x * sqrt(idg)  (= D^-1 D^{1/2} x) ----
    for (int n = tid; n < NN; n += 1024) {
        float sq = sqrtf(idg[n]);
        float4 v;
        v.x = x[(((size_t)b * CIN + cg * 4 + 0) * TT + t) * NN + n] * sq;
        v.y = x[(((size_t)b * CIN + cg * 4 + 1) * TT + t) * NN + n] * sq;
        v.z = x[(((size_t)b * CIN + cg * 4 + 2) * TT + t) * NN + n] * sq;
        v.w = x[(((size_t)b * CIN + cg * 4 + 3) * TT + t) * NN + n] * sq;
        Y[n] = v;
    }
    __syncthreads();

    // ---- three propagation passes, all LDS; dual-node fused loop ----
    const int n0 = tid, n1 = tid + 1024;
    const unsigned int rp0 = rp[n0], re0 = rp[n0 + 1];
    const unsigned int rp1 = rp[n1], re1 = rp[n1 + 1];
    const int cn0 = (int)(re0 - rp0), cn1 = (int)(re1 - rp1);
    const int mx = max(cn0, cn1);

    for (int pass = 0; pass < 3; pass++) {
        float4 a0 = Y[n0];
        float4 a1 = Y[n1];
        float sx0 = 0, sy0 = 0, sz0 = 0, sw0 = 0;
        float sx1 = 0, sy1 = 0, sz1 = 0, sw1 = 0;
        for (int k = 0; k < mx; k++) {
            if (k < cn0) {
                unsigned int g = cmp[rp0 + k];
                float w = (float)(g & 0xffffu);
                float4 y = Y[g >> 16];
                sx0 += w * y.x; sy0 += w * y.y; sz0 += w * y.z; sw0 += w * y.w;
            }
            if (k < cn1) {
                unsigned int g = cmp[rp1 + k];
                float w = (float)(g & 0xffffu);
                float4 y = Y[g >> 16];
                sx1 += w * y.x; sy1 += w * y.y; sz1 += w * y.z; sw1 += w * y.w;
            }
        }
        a0.x += sx0 * WINV; a0.y += sy0 * WINV; a0.z += sz0 * WINV; a0.w += sw0 * WINV;
        a1.x += sx1 * WINV; a1.y += sy1 * WINV; a1.z += sz1 * WINV; a1.w += sw1 * WINV;

        if (pass < 2) {
            __syncthreads();   // all reads of Y done
            float g0 = idg[n0];
            Y[n0] = make_float4(a0.x * g0, a0.y * g0, a0.z * g0, a0.w * g0);
            float g1 = idg[n1];
            Y[n1] = make_float4(a1.x * g1, a1.y * g1, a1.z * g1, a1.w * g1);
            __syncthreads();
        } else {
            // final: C3 = a * sqrt(idg), straight to global (coalesced per channel)
            float s0 = sqrtf(idg[n0]);
            float* base = C3 + ((size_t)bt * CIN + cg * 4) * NN;
            base[0 * NN + n0] = a0.x * s0;
            base[1 * NN + n0] = a0.y * s0;
            base[2 * NN + n0] = a0.z * s0;
            base[3 * NN + n0] = a0.w * s0;
            if (n1 < NN) {
                float s1 = sqrtf(idg[n1]);
                base[0 * NN + n1] = a1.x * s1;
                base[1 * NN + n1] = a1.y * s1;
                base[2 * NN + n1] = a1.z * s1;
                base[3 * NN + n1] = a1.w * s1;
            }
        }
    }
}

// =============== kernel 2: P = C3@W123 + r2*d1 + r1*d2 + b3; out = relu(P), transposed ===============
__global__ __launch_bounds__(256) void k_out(
    const float* __restrict__ C3,       // [bt][32][2000]
    const float* __restrict__ W123,     // 32x64
    const float* __restrict__ d1, const float* __restrict__ d2,
    const float* __restrict__ b3,
    const float* __restrict__ r1f, const float* __restrict__ r2f,
    float* __restrict__ out)            // [B][COUT][T][N]
{
    __shared__ float Cs[CIN][65];
    __shared__ float Ws[CIN][64];
    __shared__ float Os[64][65];
    __shared__ float d1s[64], d2s[64], b3s[64], r1s[64], r2s[64];
    const int tid = threadIdx.x;
    const int bt = blockIdx.y, b = bt >> 3, t = bt & 7;
    const int n0 = blockIdx.x * 64;

    for (int i = tid; i < CIN * 64; i += 256) {
        int ch = i >> 6, nn = i & 63;
        int n = n0 + nn;
        Cs[ch][nn] = (n < NN) ? C3[((size_t)bt * CIN + ch) * NN + n] : 0.f;
    }
    for (int i = tid; i < CIN * 64; i += 256)
        Ws[i >> 6][i & 63] = W123[i];
    if (tid < 64) {
        d1s[tid] = d1[tid];
        d2s[tid] = d2[tid];
        b3s[tid] = b3[tid];
        int n = n0 + tid;
        r1s[tid] = (n < NN) ? r1f[n] : 0.f;
        r2s[tid] = (n < NN) ? r2f[n] : 0.f;
    }
    __syncthreads();

    const int c = tid & 63, g = tid >> 6;
    for (int i = 0; i < 16; i++) {
        int nn = g * 16 + i;
        float acc = r2s[nn] * d1s[c] + r1s[nn] * d2s[c] + b3s[c];
        #pragma unroll
        for (int k = 0; k < CIN; k++) acc += Cs[k][nn] * Ws[k][c];
        Os[nn][c] = fmaxf(acc, 0.f);
    }
    __syncthreads();

    #pragma unroll
    for (int pass = 0; pass < 16; pass++) {
        int cc = g + pass * 4;
        int n = n0 + (tid & 63);
        if (n < NN)
            out[(((size_t)b * COUT + cc) * TT + t) * NN + n] = Os[tid & 63][cc];
    }
}

// ---------------- launch: exactly TWO dispatches ----------------

extern "C" void kernel_launch(void* const* d_in, const int* in_sizes, int n_in,
                              void* d_out, int out_size, void* d_ws, size_t ws_size,
                              hipStream_t stream) {
    (void)in_sizes; (void)n_in; (void)out_size; (void)ws_size;

    const float* x  = (const float*)d_in[0];
    const int*   ei = (const int*)d_in[1];
    const float* ew = (const float*)d_in[2];
    const float* W1 = (const float*)d_in[3];
    const float* b1 = (const float*)d_in[4];
    const float* W2 = (const float*)d_in[5];
    const float* b2 = (const float*)d_in[6];
    const float* W3 = (const float*)d_in[7];
    const float* b3 = (const float*)d_in[8];
    float* out = (float*)d_out;

    const int* src = ei;
    const int* dst = ei + NE;

    // workspace layout (float units) — all pure overwrites, replay-safe
    float* wsf  = (float*)d_ws;
    float* r1f  = wsf;            // 2048
    float* r2f  = wsf + 2048;     // 2048
    float* W123 = wsf + 4096;     // 2048
    float* d1   = wsf + 6144;     // 64
    float* d2   = wsf + 6208;     // 64
    float* C3   = wsf + 6272;     // 32*32*2000 floats

    k_sss<<<dim3(8, BT), dim3(1024), 0, stream>>>(
        x, src, dst, ew, W1, b1, W2, b2, W3,
        r1f, r2f, W123, d1, d2, C3);

    k_out<<<dim3(32, BT), dim3(256), 0, stream>>>(
        C3, W123, d1, d2, b3, r1f, r2f, out);
}